// Round 1
// baseline (309.838 us; speedup 1.0000x reference)
//
#include <hip/hip_runtime.h>
#include <math.h>

#define BB 8
#define CC 1024
#define PP 4096   // H*W = 64*64
#define KK 16
#define EPSF 1e-8f

// ws layout:
//   num     [B][K][C]  @ 0          (512 KiB)
//   den     [B][K]     @ 0x80000    (512 B)
//   pn      [B][K]     @ 0x80200    (512 B)
//   proto_t [B][C][K]  @ 0x100000   (512 KiB)

// ---- kernel 1: masked per-class channel sums (prototype numerators) ----
// grid 1024 = B(8) x cgroup(128); block 256 = 4 waves, wave handles 2 channels,
// lanes over pixels (coalesced). Deterministic butterfly reduce, no atomics.
__global__ __launch_bounds__(256) void k_num(const float* __restrict__ sf,
                                             const int* __restrict__ sm,
                                             float* __restrict__ num) {
    int blk  = blockIdx.x;
    int b    = blk >> 7;
    int cg   = blk & 127;
    int wave = threadIdx.x >> 6;
    int lane = threadIdx.x & 63;
    int c0   = cg * 8 + wave * 2;

    const float* f0 = sf + ((size_t)b * CC + c0) * PP;
    const float* f1 = f0 + PP;
    const int*   m  = sm + (size_t)b * PP;

    float a0[KK], a1[KK];
#pragma unroll
    for (int k = 0; k < KK; ++k) { a0[k] = 0.f; a1[k] = 0.f; }

    for (int it = 0; it < PP / 64; ++it) {
        int p   = it * 64 + lane;
        int mv  = m[p];
        float v0 = f0[p];
        float v1 = f1[p];
#pragma unroll
        for (int k = 0; k < KK; ++k) {
            float pr = (mv == k + 1) ? 1.0f : 0.0f;
            a0[k] = fmaf(pr, v0, a0[k]);
            a1[k] = fmaf(pr, v1, a1[k]);
        }
    }

#pragma unroll
    for (int k = 0; k < KK; ++k) {
#pragma unroll
        for (int s = 32; s >= 1; s >>= 1) {
            a0[k] += __shfl_xor(a0[k], s, 64);
            a1[k] += __shfl_xor(a1[k], s, 64);
        }
    }

    if (lane == 0) {
        float* o = num + (size_t)b * KK * CC + c0;
#pragma unroll
        for (int k = 0; k < KK; ++k) {
            o[(size_t)k * CC]     = a0[k];
            o[(size_t)k * CC + 1] = a1[k];
        }
    }
}

// ---- kernel 2: per-class pixel counts (denominators) ----
__global__ __launch_bounds__(256) void k_den(const int* __restrict__ sm,
                                             float* __restrict__ den) {
    int b    = blockIdx.x;
    int tid  = threadIdx.x;
    int wave = tid >> 6;
    int lane = tid & 63;
    const int* m = sm + (size_t)b * PP;

    float cnt[KK];
#pragma unroll
    for (int k = 0; k < KK; ++k) cnt[k] = 0.f;

    for (int it = 0; it < PP / 256; ++it) {
        int mv = m[it * 256 + tid];
#pragma unroll
        for (int k = 0; k < KK; ++k) cnt[k] += (mv == k + 1) ? 1.0f : 0.0f;
    }

#pragma unroll
    for (int k = 0; k < KK; ++k) {
#pragma unroll
        for (int s = 32; s >= 1; s >>= 1) cnt[k] += __shfl_xor(cnt[k], s, 64);
    }

    __shared__ float wsum[4][KK];
    if (lane == 0) {
#pragma unroll
        for (int k = 0; k < KK; ++k) wsum[wave][k] = cnt[k];
    }
    __syncthreads();
    if (tid < KK)
        den[b * KK + tid] = wsum[0][tid] + wsum[1][tid] + wsum[2][tid] + wsum[3][tid];
}

// ---- kernel 3: prototypes (num/den), transposed [b][c][k], and norms ----
__global__ __launch_bounds__(256) void k_proto(const float* __restrict__ num,
                                               const float* __restrict__ den,
                                               float* __restrict__ proto_t,
                                               float* __restrict__ pn) {
    int b   = blockIdx.x >> 4;
    int k   = blockIdx.x & 15;
    int tid = threadIdx.x;
    const float* nu = num + ((size_t)b * KK + k) * CC;
    float d = den[b * KK + k];

    float sq = 0.f;
#pragma unroll
    for (int i = 0; i < CC / 256; ++i) {
        int c = i * 256 + tid;
        float pv = nu[c] / d;
        proto_t[((size_t)b * CC + c) * KK + k] = pv;
        sq = fmaf(pv, pv, sq);
    }

#pragma unroll
    for (int s = 32; s >= 1; s >>= 1) sq += __shfl_xor(sq, s, 64);

    __shared__ float red[4];
    if ((tid & 63) == 0) red[tid >> 6] = sq;
    __syncthreads();
    if (tid == 0) pn[b * KK + k] = sqrtf(red[0] + red[1] + red[2] + red[3]);
}

// ---- kernel 4: cosine similarity + argmax ----
// grid 512 = B(8) x pgroup(64); block 256 = 64 pixels (lanes) x 4 C-chunks (waves).
// Prototypes read through wave-uniform addresses -> scalar loads (SGPR operands),
// zero LDS traffic in the hot loop.
__global__ __launch_bounds__(256) void k_match(const float* __restrict__ qf,
                                               const float* __restrict__ proto_t,
                                               const float* __restrict__ pn,
                                               int* __restrict__ out) {
    int b    = blockIdx.x >> 6;
    int pg   = blockIdx.x & 63;
    int tid  = threadIdx.x;
    int lane = tid & 63;
    int chunk = __builtin_amdgcn_readfirstlane(tid >> 6);  // force SGPR (wave-uniform)
    int px   = pg * 64 + lane;

    const float* q  = qf + ((size_t)b * CC + (size_t)chunk * 256) * PP + px;
    const float* pt = proto_t + ((size_t)b * CC + (size_t)chunk * 256) * KK;

    float dot[KK];
#pragma unroll
    for (int k = 0; k < KK; ++k) dot[k] = 0.f;
    float qs = 0.f;

    for (int ci = 0; ci < 256; ++ci) {
        float qv = q[(size_t)ci * PP];
        const float* pr = pt + ci * KK;
#pragma unroll
        for (int k = 0; k < KK; ++k) dot[k] = fmaf(pr[k], qv, dot[k]);
        qs = fmaf(qv, qv, qs);
    }

    __shared__ float red[4][64][KK + 1];  // stride 17 floats: odd -> bank-conflict-free
#pragma unroll
    for (int k = 0; k < KK; ++k) red[chunk][lane][k] = dot[k];
    red[chunk][lane][KK] = qs;
    __syncthreads();

    if (tid < 64) {
        float q2 = red[0][tid][KK] + red[1][tid][KK] + red[2][tid][KK] + red[3][tid][KK];
        float qn = sqrtf(q2);
        float bv = -INFINITY;
        int   bi = 0;
#pragma unroll
        for (int k = 0; k < KK; ++k) {
            float dk = red[0][tid][k] + red[1][tid][k] + red[2][tid][k] + red[3][tid][k];
            float s  = dk / fmaxf(pn[b * KK + k] * qn, EPSF);
            if (s > bv) { bv = s; bi = k; }  // strict '>' ascending = first-max (jnp.argmax)
        }
        out[(size_t)b * PP + pg * 64 + tid] = bi;
    }
}

extern "C" void kernel_launch(void* const* d_in, const int* in_sizes, int n_in,
                              void* d_out, int out_size, void* d_ws, size_t ws_size,
                              hipStream_t stream) {
    const float* sf = (const float*)d_in[0];  // support_features (8,1024,64,64) f32
    const int*   sm = (const int*)d_in[1];    // support_masks    (8,1,64,64)    i32
    const float* qf = (const float*)d_in[2];  // query_features   (8,1024,64,64) f32
    int* out = (int*)d_out;                   // (8,64,64) i32

    char*  ws      = (char*)d_ws;
    float* num     = (float*)(ws);
    float* den     = (float*)(ws + (512u << 10));
    float* pn      = (float*)(ws + (512u << 10) + 512);
    float* proto_t = (float*)(ws + (1u << 20));

    hipLaunchKernelGGL(k_num,   dim3(1024), dim3(256), 0, stream, sf, sm, num);
    hipLaunchKernelGGL(k_den,   dim3(8),    dim3(256), 0, stream, sm, den);
    hipLaunchKernelGGL(k_proto, dim3(128),  dim3(256), 0, stream, num, den, proto_t, pn);
    hipLaunchKernelGGL(k_match, dim3(512),  dim3(256), 0, stream, qf, proto_t, pn, out);
}